// Round 3
// baseline (569.175 us; speedup 1.0000x reference)
//
#include <hip/hip_runtime.h>

#define T_DIM 16384
#define H_DIM 2048
#define I_DIM 1408
#define NB_DIM (2 * I_DIM)   // 2816 interleaved gate/up columns

typedef _Float16 half8 __attribute__((ext_vector_type(8)));
typedef float floatx16 __attribute__((ext_vector_type(16)));

// -------- async global -> LDS, 16 bytes per lane (gfx950) --------
// LDS dest is wave-uniform base; HW writes lane l at base + l*16.
__device__ __forceinline__ void async_cp16(const _Float16* gp, _Float16* lp) {
    __builtin_amdgcn_global_load_lds(
        (const __attribute__((address_space(1))) unsigned int*)gp,
        (__attribute__((address_space(3))) unsigned int*)lp,
        16, 0, 0);
}

// -------- fp32 -> fp16 conversion of x --------
__global__ void cvt_fp16_kernel(const float* __restrict__ x, _Float16* __restrict__ xh) {
    int i = (blockIdx.x * 256 + threadIdx.x) * 8;
    const float4* p = (const float4*)(x + i);
    float4 a = p[0];
    float4 b = p[1];
    half8 o = { (_Float16)a.x, (_Float16)a.y, (_Float16)a.z, (_Float16)a.w,
                (_Float16)b.x, (_Float16)b.y, (_Float16)b.z, (_Float16)b.w };
    *(half8*)(xh + i) = o;
}

// -------- GPTQ dequant -> transposed fp16 weight Wt[n'][k], coalesced both ways --------
// qw: [K/8][N] int32 (8 nibbles along k), qz: [K/128][N/8] int32, sc: [K/128][N] f32
// interleave: n' = (n>>5)*64 + (n&31) + off  (gate off=0, up off=32); else n' = n.
__global__ void dequant_kernel(const int* __restrict__ qw, const int* __restrict__ qz,
                               const float* __restrict__ sc, _Float16* __restrict__ Wt,
                               int K, int N, int interleave, int off) {
    __shared__ half8 tile[256];                 // [64 n][4 kp]
    int t = threadIdx.x;
    int nl = t & 63, kl = t >> 6;
    int n  = blockIdx.x * 64 + nl;
    int kp = blockIdx.y * 4 + kl;
    int q = qw[kp * N + n];                     // coalesced along n
    int g = kp >> 4;                            // (kp*8)/128
    float scale = sc[g * N + n];
    int zq = (qz[g * (N >> 3) + (n >> 3)] >> (4 * (n & 7))) & 0xF;
    float zf = (float)(zq + 1);
    half8 o;
#pragma unroll
    for (int j = 0; j < 8; ++j)
        o[j] = (_Float16)(((float)((q >> (4 * j)) & 0xF) - zf) * scale);
    tile[nl * 4 + kl] = o;
    __syncthreads();
    int nl2 = t >> 2, kl2 = t & 3;
    int n2 = blockIdx.x * 64 + nl2;
    int np = interleave ? (((n2 >> 5) << 6) + (n2 & 31) + off) : n2;
    *(half8*)(Wt + (size_t)np * K + (size_t)(blockIdx.y * 4 + kl2) * 8) = tile[nl2 * 4 + kl2];
}

// ============ GEMM: 128x128 tile, BK=64, XOR-swizzled LDS, mfma 32x32x16 ============
// LDS row = 128B (8 chunks of 16B); global chunk c of row r stored at position c^(r&7).
// Staging: issue i covers rows [i*32,i*32+32); lane l of wave w loads global chunk
// (l&7)^(l>>3) of row i*32+w*8+(l>>3); lands at stored position l&7 (row&7 == l>>3).
// Wave tile 64x64 = 2x2 of 32x32. A/B frag: [m=lane&31][k=(lane>>5)*8+j], 4 ksteps/iter.
// C/D: col=lane&31, row=(reg&3)+8*(reg>>2)+4*(lane>>5)  [m74/m101].
// Grid: blockIdx.x = n-panel (small, fastest -> B L2-resident, A read ~once),
//       blockIdx.y = m-panel.

// -------- GEMM1: h = silu(gate) * up via interleaved B' [2816][2048], fp16 out --------
__launch_bounds__(256, 3)
__global__ void gemm_gateup(const _Float16* __restrict__ A,   // xh [T][H]
                            const _Float16* __restrict__ B,   // B'  [2816][H]
                            _Float16* __restrict__ h) {       // [T][I]
    __shared__ _Float16 As[128 * 64];
    __shared__ _Float16 Bs[128 * 64];
    const int t = threadIdx.x;
    const int wave = t >> 6, lane = t & 63;
    const int n0 = blockIdx.x * 128;
    const int m0 = blockIdx.y * 128;
    const int wm = wave >> 1, wn = wave & 1;

    const int srow = wave * 8 + (lane >> 3);
    const int schunk = (lane & 7) ^ (lane >> 3);
    const _Float16* ag = A + (size_t)(m0 + srow) * H_DIM + schunk * 8;
    const _Float16* bg = B + (size_t)(n0 + srow) * H_DIM + schunk * 8;
    _Float16* lA = As + wave * 512;
    _Float16* lB = Bs + wave * 512;

    const int l31 = lane & 31, h5 = lane >> 5;
    int arow64[2], arm[2], brow64[2], brm[2];
#pragma unroll
    for (int i = 0; i < 2; ++i) {
        int rA = wm * 64 + i * 32 + l31;
        arow64[i] = rA * 64; arm[i] = rA & 7;
        int rB = wn * 64 + i * 32 + l31;
        brow64[i] = rB * 64; brm[i] = rB & 7;
    }

    floatx16 acc[2][2];
#pragma unroll
    for (int mi = 0; mi < 2; ++mi)
#pragma unroll
        for (int ni = 0; ni < 2; ++ni)
#pragma unroll
            for (int r = 0; r < 16; ++r) acc[mi][ni][r] = 0.f;

    for (int kt = 0; kt < H_DIM; kt += 64) {
        __syncthreads();
#pragma unroll
        for (int i = 0; i < 4; ++i) {
            async_cp16(ag + kt + (size_t)i * 32 * H_DIM, lA + i * 2048);
            async_cp16(bg + kt + (size_t)i * 32 * H_DIM, lB + i * 2048);
        }
        __syncthreads();
#pragma unroll
        for (int kk = 0; kk < 4; ++kk) {
            const int c = h5 + kk * 2;
            half8 af[2], bf[2];
#pragma unroll
            for (int i = 0; i < 2; ++i) af[i] = *(const half8*)(As + arow64[i] + ((c ^ arm[i]) * 8));
#pragma unroll
            for (int i = 0; i < 2; ++i) bf[i] = *(const half8*)(Bs + brow64[i] + ((c ^ brm[i]) * 8));
#pragma unroll
            for (int mi = 0; mi < 2; ++mi)
#pragma unroll
                for (int ni = 0; ni < 2; ++ni)
                    acc[mi][ni] = __builtin_amdgcn_mfma_f32_32x32x16_f16(af[mi], bf[ni], acc[mi][ni], 0, 0, 0);
        }
    }

    // epilogue: ni=0 tile = gate cols, ni=1 tile = up cols of the SAME h-columns
    const int hcol = (n0 >> 1) + wn * 32 + l31;
#pragma unroll
    for (int mi = 0; mi < 2; ++mi)
#pragma unroll
        for (int r = 0; r < 16; ++r) {
            int row = m0 + wm * 64 + mi * 32 + (r & 3) + 8 * (r >> 2) + 4 * h5;
            float g = acc[mi][0][r];
            float u = acc[mi][1][r];
            float s = (g / (1.0f + __expf(-g))) * u;
            h[(size_t)row * I_DIM + hcol] = (_Float16)s;
        }
}

// -------- GEMM2: out = h @ Wd, fp32 out --------
__launch_bounds__(256, 3)
__global__ void gemm_down(const _Float16* __restrict__ A,    // h [T][I]
                          const _Float16* __restrict__ B,    // Wd_t [H][I]
                          float* __restrict__ out) {         // [T][H]
    __shared__ _Float16 As[128 * 64];
    __shared__ _Float16 Bs[128 * 64];
    const int t = threadIdx.x;
    const int wave = t >> 6, lane = t & 63;
    const int n0 = blockIdx.x * 128;
    const int m0 = blockIdx.y * 128;
    const int wm = wave >> 1, wn = wave & 1;

    const int srow = wave * 8 + (lane >> 3);
    const int schunk = (lane & 7) ^ (lane >> 3);
    const _Float16* ag = A + (size_t)(m0 + srow) * I_DIM + schunk * 8;
    const _Float16* bg = B + (size_t)(n0 + srow) * I_DIM + schunk * 8;
    _Float16* lA = As + wave * 512;
    _Float16* lB = Bs + wave * 512;

    const int l31 = lane & 31, h5 = lane >> 5;
    int arow64[2], arm[2], brow64[2], brm[2];
#pragma unroll
    for (int i = 0; i < 2; ++i) {
        int rA = wm * 64 + i * 32 + l31;
        arow64[i] = rA * 64; arm[i] = rA & 7;
        int rB = wn * 64 + i * 32 + l31;
        brow64[i] = rB * 64; brm[i] = rB & 7;
    }

    floatx16 acc[2][2];
#pragma unroll
    for (int mi = 0; mi < 2; ++mi)
#pragma unroll
        for (int ni = 0; ni < 2; ++ni)
#pragma unroll
            for (int r = 0; r < 16; ++r) acc[mi][ni][r] = 0.f;

    for (int kt = 0; kt < I_DIM; kt += 64) {
        __syncthreads();
#pragma unroll
        for (int i = 0; i < 4; ++i) {
            async_cp16(ag + kt + (size_t)i * 32 * I_DIM, lA + i * 2048);
            async_cp16(bg + kt + (size_t)i * 32 * I_DIM, lB + i * 2048);
        }
        __syncthreads();
#pragma unroll
        for (int kk = 0; kk < 4; ++kk) {
            const int c = h5 + kk * 2;
            half8 af[2], bf[2];
#pragma unroll
            for (int i = 0; i < 2; ++i) af[i] = *(const half8*)(As + arow64[i] + ((c ^ arm[i]) * 8));
#pragma unroll
            for (int i = 0; i < 2; ++i) bf[i] = *(const half8*)(Bs + brow64[i] + ((c ^ brm[i]) * 8));
#pragma unroll
            for (int mi = 0; mi < 2; ++mi)
#pragma unroll
                for (int ni = 0; ni < 2; ++ni)
                    acc[mi][ni] = __builtin_amdgcn_mfma_f32_32x32x16_f16(af[mi], bf[ni], acc[mi][ni], 0, 0, 0);
        }
    }

#pragma unroll
    for (int mi = 0; mi < 2; ++mi)
#pragma unroll
        for (int ni = 0; ni < 2; ++ni)
#pragma unroll
            for (int r = 0; r < 16; ++r) {
                int row = m0 + wm * 64 + mi * 32 + (r & 3) + 8 * (r >> 2) + 4 * h5;
                int col = n0 + wn * 64 + ni * 32 + l31;
                out[(size_t)row * H_DIM + col] = acc[mi][ni][r];
            }
}

extern "C" void kernel_launch(void* const* d_in, const int* in_sizes, int n_in,
                              void* d_out, int out_size, void* d_ws, size_t ws_size,
                              hipStream_t stream) {
    const float* x    = (const float*)d_in[0];
    const int* qw_g   = (const int*)d_in[1];
    const int* qz_g   = (const int*)d_in[2];
    const float* sc_g = (const float*)d_in[3];
    const int* qw_u   = (const int*)d_in[4];
    const int* qz_u   = (const int*)d_in[5];
    const float* sc_u = (const float*)d_in[6];
    const int* qw_d   = (const int*)d_in[7];
    const int* qz_d   = (const int*)d_in[8];
    const float* sc_d = (const float*)d_in[9];
    float* out = (float*)d_out;

    // ws (fp16): xh 64MiB | h 44MiB | B' 11MiB | Wd_t 5.5MiB
    char* ws = (char*)d_ws;
    _Float16* xh  = (_Float16*)ws;  ws += (size_t)T_DIM * H_DIM * sizeof(_Float16);
    _Float16* hh  = (_Float16*)ws;  ws += (size_t)T_DIM * I_DIM * sizeof(_Float16);
    _Float16* Bgu = (_Float16*)ws;  ws += (size_t)NB_DIM * H_DIM * sizeof(_Float16);
    _Float16* Wd  = (_Float16*)ws;  ws += (size_t)I_DIM * H_DIM * sizeof(_Float16);

    cvt_fp16_kernel<<<(T_DIM * H_DIM) / 2048, 256, 0, stream>>>(x, xh);
    dequant_kernel<<<dim3(I_DIM / 64, H_DIM / 32), 256, 0, stream>>>(qw_g, qz_g, sc_g, Bgu, H_DIM, I_DIM, 1, 0);
    dequant_kernel<<<dim3(I_DIM / 64, H_DIM / 32), 256, 0, stream>>>(qw_u, qz_u, sc_u, Bgu, H_DIM, I_DIM, 1, 32);
    dequant_kernel<<<dim3(H_DIM / 64, I_DIM / 32), 256, 0, stream>>>(qw_d, qz_d, sc_d, Wd, I_DIM, H_DIM, 0, 0);
    gemm_gateup<<<dim3(NB_DIM / 128, T_DIM / 128), 256, 0, stream>>>(xh, Bgu, hh);
    gemm_down<<<dim3(H_DIM / 128, T_DIM / 128), 256, 0, stream>>>(hh, Wd, out);
}

// Round 4
// 513.814 us; speedup vs baseline: 1.1077x; 1.1077x over previous
//
#include <hip/hip_runtime.h>

#define T_DIM 16384
#define H_DIM 2048
#define I_DIM 1408
#define NB_DIM (2 * I_DIM)   // 2816 interleaved gate/up columns

typedef _Float16 half8 __attribute__((ext_vector_type(8)));
typedef float floatx4 __attribute__((ext_vector_type(4)));

// -------- async global -> LDS, 16 bytes per lane (gfx950) --------
// LDS dest is wave-uniform base; HW writes lane l at base + l*16.
__device__ __forceinline__ void async_cp16(const _Float16* gp, _Float16* lp) {
    __builtin_amdgcn_global_load_lds(
        (const __attribute__((address_space(1))) unsigned int*)gp,
        (__attribute__((address_space(3))) unsigned int*)lp,
        16, 0, 0);
}

// -------- fp32 -> fp16 conversion of x --------
__global__ void cvt_fp16_kernel(const float* __restrict__ x, _Float16* __restrict__ xh) {
    int i = (blockIdx.x * 256 + threadIdx.x) * 8;
    const float4* p = (const float4*)(x + i);
    float4 a = p[0];
    float4 b = p[1];
    half8 o = { (_Float16)a.x, (_Float16)a.y, (_Float16)a.z, (_Float16)a.w,
                (_Float16)b.x, (_Float16)b.y, (_Float16)b.z, (_Float16)b.w };
    *(half8*)(xh + i) = o;
}

// -------- GPTQ dequant -> transposed fp16 weight Wt[n'][k], coalesced both ways --------
// qw: [K/8][N] int32 (8 nibbles along k), qz: [K/128][N/8] int32, sc: [K/128][N] f32
// interleave: n' = (n>>5)*64 + (n&31) + off  (gate off=0, up off=32); else n' = n.
__global__ void dequant_kernel(const int* __restrict__ qw, const int* __restrict__ qz,
                               const float* __restrict__ sc, _Float16* __restrict__ Wt,
                               int K, int N, int interleave, int off) {
    __shared__ half8 tile[256];                 // [64 n][4 kp]
    int t = threadIdx.x;
    int nl = t & 63, kl = t >> 6;
    int n  = blockIdx.x * 64 + nl;
    int kp = blockIdx.y * 4 + kl;
    int q = qw[kp * N + n];                     // coalesced along n
    int g = kp >> 4;                            // (kp*8)/128
    float scale = sc[g * N + n];
    int zq = (qz[g * (N >> 3) + (n >> 3)] >> (4 * (n & 7))) & 0xF;
    float zf = (float)(zq + 1);
    half8 o;
#pragma unroll
    for (int j = 0; j < 8; ++j)
        o[j] = (_Float16)(((float)((q >> (4 * j)) & 0xF) - zf) * scale);
    tile[nl * 4 + kl] = o;
    __syncthreads();
    int nl2 = t >> 2, kl2 = t & 3;
    int n2 = blockIdx.x * 64 + nl2;
    int np = interleave ? (((n2 >> 5) << 6) + (n2 & 31) + off) : n2;
    *(half8*)(Wt + (size_t)np * K + (size_t)(blockIdx.y * 4 + kl2) * 8) = tile[nl2 * 4 + kl2];
}

// ============ GEMM: 128x128 tile, BK=64, XOR-swizzled LDS, mfma 16x16x32 ============
// (round-2 structure: measured 0 bank conflicts)
// LDS row = 128B (8 chunks of 16B); global chunk c of row r stored at position c^(r&7).
// Staging: issue i covers rows [i*32,i*32+32); lane l of wave w loads global chunk
// (l&7)^(l>>3) of row i*32+w*8+(l>>3); lands at stored position l&7.
// Grid: 1D, grouped decode — GM=64 m-panels per super-group, m fastest within group,
// so ~12 co-resident n-panels share each A-tile (A window 32MB + B in L3).

// -------- GEMM1: h = silu(gate) * up via interleaved B' [2816][2048], fp16 out --------
__launch_bounds__(256, 4)
__global__ void gemm_gateup(const _Float16* __restrict__ A,   // xh [T][H]
                            const _Float16* __restrict__ B,   // B'  [2816][H]
                            _Float16* __restrict__ h) {       // [T][I]
    __shared__ _Float16 As[128 * 64];
    __shared__ _Float16 Bs[128 * 64];
    const int t = threadIdx.x;
    const int wave = t >> 6, lane = t & 63;

    // grouped grid decode: supers of 64 m-panels x 22 n-panels, m fastest
    const int NPAN = NB_DIM / 128;              // 22
    const int per_super = 64 * NPAN;            // 1408
    int id = blockIdx.x;
    int sup = id / per_super;
    int rem = id - sup * per_super;
    const int m0 = (sup * 64 + (rem & 63)) * 128;
    const int n_p = rem >> 6;
    const int n0 = n_p * 128;
    const int wm = wave >> 1, wn = wave & 1;

    const int srow = wave * 8 + (lane >> 3);
    const int schunk = (lane & 7) ^ (lane >> 3);
    const _Float16* ag = A + (size_t)(m0 + srow) * H_DIM + schunk * 8;
    const _Float16* bg = B + (size_t)(n0 + srow) * H_DIM + schunk * 8;
    _Float16* lA = As + wave * 512;
    _Float16* lB = Bs + wave * 512;

    const int q4 = lane >> 4, l15 = lane & 15;
    int aoff[4], boff[4];
#pragma unroll
    for (int i = 0; i < 4; ++i) {
        int rA = wm * 64 + i * 16 + l15;
        aoff[i] = rA * 64 + ((q4 ^ (rA & 7)) * 8);
        int rB = wn * 64 + i * 16 + l15;
        boff[i] = rB * 64 + ((q4 ^ (rB & 7)) * 8);
    }

    floatx4 zero = {0.f, 0.f, 0.f, 0.f};
    floatx4 acc[4][4];
#pragma unroll
    for (int mi = 0; mi < 4; ++mi)
#pragma unroll
        for (int ni = 0; ni < 4; ++ni) acc[mi][ni] = zero;

    for (int kt = 0; kt < H_DIM; kt += 64) {
        __syncthreads();
#pragma unroll
        for (int i = 0; i < 4; ++i) {
            async_cp16(ag + kt + (size_t)i * 32 * H_DIM, lA + i * 2048);
            async_cp16(bg + kt + (size_t)i * 32 * H_DIM, lB + i * 2048);
        }
        __syncthreads();
#pragma unroll
        for (int kk = 0; kk < 2; ++kk) {
            half8 af[4], bf[4];
#pragma unroll
            for (int i = 0; i < 4; ++i) af[i] = *(const half8*)(As + (aoff[i] ^ (kk * 32)));
#pragma unroll
            for (int i = 0; i < 4; ++i) bf[i] = *(const half8*)(Bs + (boff[i] ^ (kk * 32)));
#pragma unroll
            for (int mi = 0; mi < 4; ++mi)
#pragma unroll
                for (int ni = 0; ni < 4; ++ni)
                    acc[mi][ni] = __builtin_amdgcn_mfma_f32_16x16x32_f16(af[mi], bf[ni], acc[mi][ni], 0, 0, 0);
        }
    }

    // epilogue: ni 0,1 = gate, ni 2,3 = up of the same h-columns
    const int rq = q4 * 4;
#pragma unroll
    for (int mi = 0; mi < 4; ++mi)
#pragma unroll
        for (int nc = 0; nc < 2; ++nc)
#pragma unroll
            for (int r = 0; r < 4; ++r) {
                int row = m0 + wm * 64 + mi * 16 + rq + r;
                int col = n_p * 64 + wn * 32 + nc * 16 + l15;
                float g = acc[mi][nc][r];
                float u = acc[mi][nc + 2][r];
                float s = (g / (1.0f + __expf(-g))) * u;
                h[(size_t)row * I_DIM + col] = (_Float16)s;
            }
}

// -------- GEMM2: out = h @ Wd, fp32 out --------
__launch_bounds__(256, 4)
__global__ void gemm_down(const _Float16* __restrict__ A,    // h [T][I]
                          const _Float16* __restrict__ B,    // Wd_t [H][I]
                          float* __restrict__ out) {         // [T][H]
    __shared__ _Float16 As[128 * 64];
    __shared__ _Float16 Bs[128 * 64];
    const int t = threadIdx.x;
    const int wave = t >> 6, lane = t & 63;

    const int NPAN = H_DIM / 128;               // 16
    const int per_super = 64 * NPAN;            // 1024
    int id = blockIdx.x;
    int sup = id / per_super;
    int rem = id - sup * per_super;
    const int m0 = (sup * 64 + (rem & 63)) * 128;
    const int n0 = (rem >> 6) * 128;
    const int wm = wave >> 1, wn = wave & 1;

    const int srow = wave * 8 + (lane >> 3);
    const int schunk = (lane & 7) ^ (lane >> 3);
    const _Float16* ag = A + (size_t)(m0 + srow) * I_DIM + schunk * 8;
    const _Float16* bg = B + (size_t)(n0 + srow) * I_DIM + schunk * 8;
    _Float16* lA = As + wave * 512;
    _Float16* lB = Bs + wave * 512;

    const int q4 = lane >> 4, l15 = lane & 15;
    int aoff[4], boff[4];
#pragma unroll
    for (int i = 0; i < 4; ++i) {
        int rA = wm * 64 + i * 16 + l15;
        aoff[i] = rA * 64 + ((q4 ^ (rA & 7)) * 8);
        int rB = wn * 64 + i * 16 + l15;
        boff[i] = rB * 64 + ((q4 ^ (rB & 7)) * 8);
    }

    floatx4 zero = {0.f, 0.f, 0.f, 0.f};
    floatx4 acc[4][4];
#pragma unroll
    for (int mi = 0; mi < 4; ++mi)
#pragma unroll
        for (int ni = 0; ni < 4; ++ni) acc[mi][ni] = zero;

    for (int kt = 0; kt < I_DIM; kt += 64) {
        __syncthreads();
#pragma unroll
        for (int i = 0; i < 4; ++i) {
            async_cp16(ag + kt + (size_t)i * 32 * I_DIM, lA + i * 2048);
            async_cp16(bg + kt + (size_t)i * 32 * I_DIM, lB + i * 2048);
        }
        __syncthreads();
#pragma unroll
        for (int kk = 0; kk < 2; ++kk) {
            half8 af[4], bf[4];
#pragma unroll
            for (int i = 0; i < 4; ++i) af[i] = *(const half8*)(As + (aoff[i] ^ (kk * 32)));
#pragma unroll
            for (int i = 0; i < 4; ++i) bf[i] = *(const half8*)(Bs + (boff[i] ^ (kk * 32)));
#pragma unroll
            for (int mi = 0; mi < 4; ++mi)
#pragma unroll
                for (int ni = 0; ni < 4; ++ni)
                    acc[mi][ni] = __builtin_amdgcn_mfma_f32_16x16x32_f16(af[mi], bf[ni], acc[mi][ni], 0, 0, 0);
        }
    }

    const int rq = q4 * 4;
#pragma unroll
    for (int mi = 0; mi < 4; ++mi)
#pragma unroll
        for (int ni = 0; ni < 4; ++ni)
#pragma unroll
            for (int r = 0; r < 4; ++r) {
                int row = m0 + wm * 64 + mi * 16 + rq + r;
                int col = n0 + wn * 64 + ni * 16 + l15;
                out[(size_t)row * H_DIM + col] = acc[mi][ni][r];
            }
}

extern "C" void kernel_launch(void* const* d_in, const int* in_sizes, int n_in,
                              void* d_out, int out_size, void* d_ws, size_t ws_size,
                              hipStream_t stream) {
    const float* x    = (const float*)d_in[0];
    const int* qw_g   = (const int*)d_in[1];
    const int* qz_g   = (const int*)d_in[2];
    const float* sc_g = (const float*)d_in[3];
    const int* qw_u   = (const int*)d_in[4];
    const int* qz_u   = (const int*)d_in[5];
    const float* sc_u = (const float*)d_in[6];
    const int* qw_d   = (const int*)d_in[7];
    const int* qz_d   = (const int*)d_in[8];
    const float* sc_d = (const float*)d_in[9];
    float* out = (float*)d_out;

    // ws (fp16): xh 64MiB | h 44MiB | B' 11MiB | Wd_t 5.5MiB
    char* ws = (char*)d_ws;
    _Float16* xh  = (_Float16*)ws;  ws += (size_t)T_DIM * H_DIM * sizeof(_Float16);
    _Float16* hh  = (_Float16*)ws;  ws += (size_t)T_DIM * I_DIM * sizeof(_Float16);
    _Float16* Bgu = (_Float16*)ws;  ws += (size_t)NB_DIM * H_DIM * sizeof(_Float16);
    _Float16* Wd  = (_Float16*)ws;  ws += (size_t)I_DIM * H_DIM * sizeof(_Float16);

    cvt_fp16_kernel<<<(T_DIM * H_DIM) / 2048, 256, 0, stream>>>(x, xh);
    dequant_kernel<<<dim3(I_DIM / 64, H_DIM / 32), 256, 0, stream>>>(qw_g, qz_g, sc_g, Bgu, H_DIM, I_DIM, 1, 0);
    dequant_kernel<<<dim3(I_DIM / 64, H_DIM / 32), 256, 0, stream>>>(qw_u, qz_u, sc_u, Bgu, H_DIM, I_DIM, 1, 32);
    dequant_kernel<<<dim3(H_DIM / 64, I_DIM / 32), 256, 0, stream>>>(qw_d, qz_d, sc_d, Wd, I_DIM, H_DIM, 0, 0);
    gemm_gateup<<<(T_DIM / 128) * (NB_DIM / 128), 256, 0, stream>>>(xh, Bgu, hh);
    gemm_down<<<(T_DIM / 128) * (H_DIM / 128), 256, 0, stream>>>(hh, Wd, out);
}